// Round 11
// baseline (51.639 us; speedup 1.0000x reference)
//
#include <hip/hip_runtime.h>
#include <cstdint>
#include <cstddef>

typedef short short8 __attribute__((ext_vector_type(8)));
typedef float f32x4 __attribute__((ext_vector_type(4)));

#define BB 16
#define SS 512
#define TT 64
#define LL 64
#define UU 128
#define NV 40000

// ws layout (bytes) — WT region retired (W_trans frags built in-register)
#define WHT_OFF   0u                        // W_ht frags: 64 x 1KB = 64KB
#define WREL_OFF  (WHT_OFF + 65536u)        // W_rel frags: 32 x 1KB = 32KB
#define TE_OFF    (WREL_OFF + 32768u)       // te table bf16: 10.24MB

__device__ __forceinline__ unsigned short f2bf(float x) {  // rtne f32->bf16
  unsigned u = __float_as_uint(x);
  unsigned r = ((u >> 16) & 1u) + 0x7FFFu;
  return (unsigned short)((u + r) >> 16);
}
__device__ __forceinline__ float ftanh(float x) {  // 1 - 2/(e^2x+1)
  float e = __expf(2.0f * x);
  return 1.0f - __fdividef(2.0f, e + 1.0f);
}
__device__ __forceinline__ unsigned cvtpk(float a, float b) {
  unsigned r;
  asm("v_cvt_pk_bf16_f32 %0, %1, %2" : "=v"(r) : "v"(a), "v"(b));
  return r;
}
template<int CTRL>
__device__ __forceinline__ float dpp_mov(float x) {
  return __int_as_float(__builtin_amdgcn_update_dpp(
      0, __float_as_int(x), CTRL, 0xF, 0xF, true));
}
__device__ __forceinline__ float row16_sum(float x) {  // verified r1-r10
  x += dpp_mov<0xB1>(x);
  x += dpp_mov<0x4E>(x);
  x += dpp_mov<0x141>(x);
  x += dpp_mov<0x140>(x);
  return x;
}
__device__ __forceinline__ float full64_sum(float x) {
  x = row16_sum(x);
  x += __shfl_xor(x, 16, 64);
  x += __shfl_xor(x, 32, 64);
  return x;
}
__device__ __forceinline__ float full64_max(float x) {
  x = fmaxf(x, dpp_mov<0xB1>(x));
  x = fmaxf(x, dpp_mov<0x4E>(x));
  x = fmaxf(x, dpp_mov<0x141>(x));
  x = fmaxf(x, dpp_mov<0x140>(x));
  x = fmaxf(x, __shfl_xor(x, 16, 64));
  x = fmaxf(x, __shfl_xor(x, 32, 64));
  return x;
}

// ---- prep_te: R10 VERBATIM (verified). 417 blocks x 512 threads. ----------
__launch_bounds__(512, 8)
__global__ void prep_te(const float* __restrict__ emb_f32,
                        const float* __restrict__ Wt,
                        const float* __restrict__ Wht,
                        const float* __restrict__ Wrel,
                        const float* __restrict__ b_trans,
                        unsigned char* __restrict__ ws,
                        unsigned short* __restrict__ te_g) {
  __shared__ unsigned short TEB[96 * 128];   // 24KB
  const int tid  = threadIdx.x;
  const int base = blockIdx.x * 96;
  const int w    = tid >> 6;      // wave 0..7
  const int lane = tid & 63;
  const int li   = lane & 15;
  const int lg   = lane >> 4;
  const int nt   = w;             // wave owns n-tile w, all 6 row-tiles

  float4 xv[3], yv[3];
  #pragma unroll
  for (int j = 0; j < 3; ++j) {
    int o = tid + j * 512, row = o >> 4, pc = o & 15;
    int grow = base + row; if (grow > NV - 1) grow = NV - 1;
    int clog = pc ^ (row & 15);
    const float* fb = emb_f32 + (size_t)grow * UU + clog * 8;
    xv[j] = *reinterpret_cast<const float4*>(fb);
    yv[j] = *reinterpret_cast<const float4*>(fb + 4);
  }
  short8 B1h[4];
  #pragma unroll
  for (int kt = 0; kt < 4; ++kt) {
    #pragma unroll
    for (int j = 0; j < 8; ++j)
      B1h[kt][j] = (short)f2bf(Wt[(size_t)(kt * 32 + lg * 8 + j) * UU + nt * 16 + li]);
  }
  #pragma unroll
  for (int j = 0; j < 3; ++j) {
    int o = tid + j * 512;
    uint4 pk = { cvtpk(xv[j].x, xv[j].y), cvtpk(xv[j].z, xv[j].w),
                 cvtpk(yv[j].x, yv[j].y), cvtpk(yv[j].z, yv[j].w) };
    *reinterpret_cast<uint4*>(&TEB[o * 8]) = pk;
  }
  const float4 btr4 = *reinterpret_cast<const float4*>(b_trans + nt * 16 + lg * 4);
  __syncthreads();

  f32x4 acc[6];
  #pragma unroll
  for (int q = 0; q < 6; ++q) acc[q] = f32x4{0.f, 0.f, 0.f, 0.f};
  #pragma unroll
  for (int kt = 0; kt < 4; ++kt) {
    #pragma unroll
    for (int q = 0; q < 6; ++q) {
      const short8 b = *reinterpret_cast<const short8*>(
          &TEB[(q * 16 + li) * 128 + (((kt * 4 + lg) ^ li) << 3)]);
      acc[q] = __builtin_amdgcn_mfma_f32_16x16x32_bf16(B1h[kt], b, acc[q], 0, 0, 0);
    }
  }

  #pragma unroll
  for (int q = 0; q < 6; ++q) {
    int row  = q * 16 + li;
    int grow = base + row; if (grow > NV - 1) grow = NV - 1;
    float v0 = ftanh(acc[q][0] + btr4.x);
    float v1 = ftanh(acc[q][1] + btr4.y);
    float v2 = ftanh(acc[q][2] + btr4.z);
    float v3 = ftanh(acc[q][3] + btr4.w);
    uint2 pk = { cvtpk(v0, v1), cvtpk(v2, v3) };
    *reinterpret_cast<uint2*>(te_g + (size_t)grow * UU + nt * 16 + lg * 4) = pk;
  }

  if (blockIdx.x < 12) {
    int slot = blockIdx.x * 512 + tid;          // 0..6143
    const float* W;
    unsigned char* fb;
    if (slot < 4096) { W = Wht;  fb = ws + WHT_OFF; }
    else             { W = Wrel; fb = ws + WREL_OFF; slot -= 4096; }
    int ln = slot & 63, pair = slot >> 6;
    int n  = (pair & 7) * 16 + (ln & 15);
    int k0 = (pair >> 3) * 32 + (ln >> 4) * 8;
    short8 hv;
    #pragma unroll
    for (int j = 0; j < 8; ++j)
      hv[j] = (short)f2bf(W[(size_t)(k0 + j) * UU + n]);
    *reinterpret_cast<short8*>(fb + (size_t)pair * 1024 + ln * 16) = hv;
  }
}

// ---- R10-verbatim phase bodies as helpers ---------------------------------
// GEMM2 + e_weight partials (writes EWt). Wc = prefetched first W-frag.
__device__ __forceinline__ void gemm2_ew(
    const unsigned short* TEB, const unsigned char* whtb,
    const unsigned char* wrlb, short8 Wc, int nt, int mh, int li, int lg,
    int lane, float bhv, float brlv, float (*EWt)[64]) {
  f32x4 accH[2] = {{0.f,0.f,0.f,0.f},{0.f,0.f,0.f,0.f}};
  f32x4 accR[2] = {{0.f,0.f,0.f,0.f},{0.f,0.f,0.f,0.f}};
  #pragma unroll
  for (int kt = 0; kt < 8; ++kt) {   // head_tail: K=256
    short8 Wn;
    if (kt < 7)
      Wn = *reinterpret_cast<const short8*>(
          whtb + (size_t)((kt + 1) * 8 + nt) * 1024 + lane * 16);
    else
      Wn = *reinterpret_cast<const short8*>(
          wrlb + (size_t)nt * 1024 + lane * 16);
    const int koff = (kt < 4) ? 0 : 2;
    const int c16  = (kt & 3) * 4 + lg;
    #pragma unroll
    for (int mi = 0; mi < 2; ++mi) {
      const int row = 48 * (mh + mi) + 3 * li + koff;
      const short8 a = *reinterpret_cast<const short8*>(
          &TEB[row * 128 + ((c16 ^ (row & 15)) << 3)]);
      accH[mi] = __builtin_amdgcn_mfma_f32_16x16x32_bf16(a, Wc, accH[mi], 0, 0, 0);
    }
    Wc = Wn;
  }
  #pragma unroll
  for (int kt = 0; kt < 4; ++kt) {   // relation: K=128, rows 3l+1
    short8 Wn;
    if (kt < 3)
      Wn = *reinterpret_cast<const short8*>(
          wrlb + (size_t)((kt + 1) * 8 + nt) * 1024 + lane * 16);
    const int c16 = kt * 4 + lg;
    #pragma unroll
    for (int mi = 0; mi < 2; ++mi) {
      const int row = 48 * (mh + mi) + 3 * li + 1;
      const short8 a = *reinterpret_cast<const short8*>(
          &TEB[row * 128 + ((c16 ^ (row & 15)) << 3)]);
      accR[mi] = __builtin_amdgcn_mfma_f32_16x16x32_bf16(a, Wc, accR[mi], 0, 0, 0);
    }
    Wc = Wn;
  }
  #pragma unroll
  for (int mi = 0; mi < 2; ++mi) {
    #pragma unroll
    for (int r = 0; r < 4; ++r) {
      float p = ftanh(accH[mi][r] + bhv) * (accR[mi][r] + brlv);
      p = row16_sum(p);
      if (li == 0) EWt[nt][(mh + mi) * 16 + lg * 4 + r] = p;
    }
  }
}

// redundant per-wave softmax + weighted sum into PART (R10 verbatim).
__device__ __forceinline__ void softmax_wsum(
    const float (*EWt)[64], float (*PART)[256], const unsigned short* TEB,
    int tid, int w, int lane) {
  float alpha;
  {
    float e = 0.f;
    #pragma unroll
    for (int n = 0; n < 8; ++n) e += EWt[n][lane];
    float mx = full64_max(e);
    float ex = __expf(e - mx);
    float sm = full64_sum(ex);
    alpha = ex / sm;
  }
  int cp  = tid & 127, lgp = w >> 1;
  int c0  = cp << 1;
  int k   = (c0 >> 7) << 1;              // head rows 3l, tail rows 3l+2
  int cc  = c0 & 127;
  int w8  = cc >> 3, bofs = (cc & 7) << 1;
  float o0 = 0.f, o1 = 0.f;
  #pragma unroll
  for (int j = 0; j < 8; ++j) {
    int l = lgp * 8 + j;
    float al = __int_as_float(
        __builtin_amdgcn_readlane(__float_as_int(alpha), l));
    int row = 3 * l + k;
    unsigned u = *reinterpret_cast<const unsigned*>(
        reinterpret_cast<const char*>(TEB) + row * 256 +
        (((w8 ^ (row & 15)) << 4) | bofs));
    o0 = fmaf(al, __uint_as_float(u << 16), o0);
    o1 = fmaf(al, __uint_as_float(u & 0xFFFF0000u), o1);
  }
  *reinterpret_cast<float2*>(&PART[lgp][c0]) = make_float2(o0, o1);
}

// scatter: participating waves fold the 8-way reduce (R10 verbatim).
__device__ __forceinline__ void scatter_out(
    const float (*PART)[256], const int* match, int nm, int b, int w,
    int lane, float* out) {
  if (w < nm) {
    float4 v = {0.f, 0.f, 0.f, 0.f};
    #pragma unroll
    for (int g = 0; g < 8; ++g) {
      float4 p = reinterpret_cast<const float4*>(&PART[g][0])[lane];
      v.x += p.x; v.y += p.y; v.z += p.z; v.w += p.w;
    }
    for (int q = w; q < nm; q += 16) {
      int s = match[q];
      reinterpret_cast<float4*>(out + ((size_t)(b * SS + s)) * 256)[lane] = v;
    }
  }
}

// ---- fused: 512 blocks x 1024 threads, 2 (b,t) tiles per block ------------
// All blocks resident in ONE round (2/CU).  bt1's te gathers are ISSUED right
// after GEMM2(bt0)'s MFMAs (latency hides under ew/softmax/wsum, ~2-3k cy)
// and WRITTEN to TEB after the last bt0 TEB read; scatter(bt0) shares that
// window.  Removes the exposed stage chain for half the tiles + the second
// occupancy round.  Phase bodies are R10-verbatim helpers.  6 barriers / 2 bt.
// VGPR budget: 32 (R10) + 12 (sv1) + 3 (tok1) ~ 47 < 64 — no spill (R2's
// failure mode checked via FETCH_SIZE staying flat).
__launch_bounds__(1024, 8)
__global__ void fused_bt(const int* __restrict__ triples,
                         const unsigned short* __restrict__ te_g,
                         const float* __restrict__ b_ht,
                         const float* __restrict__ b_rel,
                         const int* __restrict__ sent_triples,
                         const unsigned char* __restrict__ wsr,
                         float* __restrict__ out) {
  __shared__ unsigned short TEB[192 * 128];    // 48KB
  __shared__ float EWt[8][64];                 // 2KB
  __shared__ float PART[8][256];               // 8KB
  __shared__ int MATCH[2][512];                // 4KB
  __shared__ int NM[2];

  const int tid  = threadIdx.x;
  const int bt0  = blockIdx.x * 2;
  const int w    = tid >> 6;
  const int lane = tid & 63;
  const int li   = lane & 15;
  const int lg   = lane >> 4;
  const int nt   = w & 7;
  const int rh   = w >> 3;
  const int mh   = rh * 2;
  const int b    = bt0 >> 6;
  const int t0   = bt0 & 63;       // even; t1 = t0+1 <= 63

  // entry: tokens for BOTH tiles (broadcast-coalesced), sent_triples once
  int tok0[3], tok1[3];
  #pragma unroll
  for (int j = 0; j < 3; ++j) {
    int row = (tid + j * 1024) >> 4;
    tok0[j] = triples[(size_t)bt0 * 192 + row];
    tok1[j] = triples[(size_t)(bt0 + 1) * 192 + row];
  }
  int sidx = -1;
  if (tid < SS) sidx = sent_triples[(size_t)b * SS + tid];
  if (tid < 2) NM[tid] = 0;

  // ---- stage bt0 (R10-verbatim pattern) ----------------------------------
  {
    short8 sv[3];
    #pragma unroll
    for (int j = 0; j < 3; ++j) {
      int o = tid + j * 1024, row = o >> 4, pc = o & 15;
      int clog = pc ^ (row & 15);
      sv[j] = *reinterpret_cast<const short8*>(
          te_g + (size_t)tok0[j] * UU + clog * 8);
    }
    #pragma unroll
    for (int j = 0; j < 3; ++j)
      *reinterpret_cast<short8*>(&TEB[(tid + j * 1024) * 8]) = sv[j];
  }

  const unsigned char* whtb = wsr + WHT_OFF;
  const unsigned char* wrlb = wsr + WREL_OFF;
  const float bhv  = b_ht[nt * 16 + li];
  const float brlv = b_rel[nt * 16 + li];
  short8 Wc = *reinterpret_cast<const short8*>(
      whtb + (size_t)nt * 1024 + lane * 16);
  __syncthreads();  // (b1) TEB(bt0) + NM ready

  // match-find for BOTH tiles from the single sidx (overlaps GEMM2(bt0))
  if (sidx == t0)     MATCH[0][atomicAdd(&NM[0], 1)] = tid;
  if (sidx == t0 + 1) MATCH[1][atomicAdd(&NM[1], 1)] = tid;

  // ============ iteration 0: GEMM2(bt0) + ew ==============================
  gemm2_ew(TEB, whtb, wrlb, Wc, nt, mh, li, lg, lane, bhv, brlv, EWt);

  // ---- ISSUE bt1 gathers; results used only after b3 ---------------------
  short8 sv1[3];
  #pragma unroll
  for (int j = 0; j < 3; ++j) {
    int o = tid + j * 1024, row = o >> 4, pc = o & 15;
    int clog = pc ^ (row & 15);
    sv1[j] = *reinterpret_cast<const short8*>(
        te_g + (size_t)tok1[j] * UU + clog * 8);
  }
  __syncthreads();  // (b2) EWt(bt0) ready

  softmax_wsum(EWt, PART, TEB, tid, w, lane);
  __syncthreads();  // (b3) PART(bt0) ready; last TEB(bt0) reads done

  // ---- write TEB(bt1) + prefetch W + scatter(bt0) in one window ----------
  #pragma unroll
  for (int j = 0; j < 3; ++j)
    *reinterpret_cast<short8*>(&TEB[(tid + j * 1024) * 8]) = sv1[j];
  Wc = *reinterpret_cast<const short8*>(
      whtb + (size_t)nt * 1024 + lane * 16);
  scatter_out(PART, MATCH[0], NM[0], b, w, lane, out);
  __syncthreads();  // (b4) TEB(bt1) ready; PART free

  // ============ iteration 1: GEMM2(bt1) + ew ==============================
  gemm2_ew(TEB, whtb, wrlb, Wc, nt, mh, li, lg, lane, bhv, brlv, EWt);
  __syncthreads();  // (b5) EWt(bt1) ready

  softmax_wsum(EWt, PART, TEB, tid, w, lane);
  __syncthreads();  // (b6) PART(bt1) ready

  scatter_out(PART, MATCH[1], NM[1], b, w, lane, out);
}

extern "C" void kernel_launch(void* const* d_in, const int* in_sizes, int n_in,
                              void* d_out, int out_size, void* d_ws, size_t ws_size,
                              hipStream_t stream) {
  const int*   triples      = (const int*)d_in[1];
  const int*   sent_triples = (const int*)d_in[2];
  const float* emb_table    = (const float*)d_in[3];
  const float* W_trans      = (const float*)d_in[4];
  const float* b_trans      = (const float*)d_in[5];
  const float* W_ht         = (const float*)d_in[6];
  const float* b_ht         = (const float*)d_in[7];
  const float* W_rel        = (const float*)d_in[8];
  const float* b_rel        = (const float*)d_in[9];
  float* out = (float*)d_out;
  unsigned char* ws = (unsigned char*)d_ws;
  unsigned short* te_g = (unsigned short*)(ws + TE_OFF);

  prep_te<<<(NV + 95) / 96, 512, 0, stream>>>(
      emb_table, W_trans, W_ht, W_rel, b_trans, ws, te_g);
  fused_bt<<<BB * TT / 2, 1024, 0, stream>>>(
      triples, te_g, b_ht, b_rel, sent_triples, ws, out);
}

// Round 12
// 40.657 us; speedup vs baseline: 1.2701x; 1.2701x over previous
//
#include <hip/hip_runtime.h>
#include <cstdint>
#include <cstddef>

typedef short short8 __attribute__((ext_vector_type(8)));
typedef float f32x4 __attribute__((ext_vector_type(4)));

#define BB 16
#define SS 512
#define TT 64
#define LL 64
#define UU 128
#define NV 40000

// ws layout (bytes) — WT region retired (W_trans frags built in-register)
#define WHT_OFF   0u                        // W_ht frags: 64 x 1KB = 64KB
#define WREL_OFF  (WHT_OFF + 65536u)        // W_rel frags: 32 x 1KB = 32KB
#define TE_OFF    (WREL_OFF + 32768u)       // te table bf16: 10.24MB

__device__ __forceinline__ unsigned short f2bf(float x) {  // rtne f32->bf16
  unsigned u = __float_as_uint(x);
  unsigned r = ((u >> 16) & 1u) + 0x7FFFu;
  return (unsigned short)((u + r) >> 16);
}
__device__ __forceinline__ float ftanh(float x) {  // 1 - 2/(e^2x+1)
  float e = __expf(2.0f * x);
  return 1.0f - __fdividef(2.0f, e + 1.0f);
}
__device__ __forceinline__ unsigned cvtpk(float a, float b) {
  unsigned r;
  asm("v_cvt_pk_bf16_f32 %0, %1, %2" : "=v"(r) : "v"(a), "v"(b));
  return r;
}
template<int CTRL>
__device__ __forceinline__ float dpp_mov(float x) {
  return __int_as_float(__builtin_amdgcn_update_dpp(
      0, __float_as_int(x), CTRL, 0xF, 0xF, true));
}
__device__ __forceinline__ float row16_sum(float x) {  // verified r1-r11
  x += dpp_mov<0xB1>(x);
  x += dpp_mov<0x4E>(x);
  x += dpp_mov<0x141>(x);
  x += dpp_mov<0x140>(x);
  return x;
}
__device__ __forceinline__ float full64_sum(float x) {
  x = row16_sum(x);
  x += __shfl_xor(x, 16, 64);
  x += __shfl_xor(x, 32, 64);
  return x;
}
__device__ __forceinline__ float full64_max(float x) {
  x = fmaxf(x, dpp_mov<0xB1>(x));
  x = fmaxf(x, dpp_mov<0x4E>(x));
  x = fmaxf(x, dpp_mov<0x141>(x));
  x = fmaxf(x, dpp_mov<0x140>(x));
  x = fmaxf(x, __shfl_xor(x, 16, 64));
  x = fmaxf(x, __shfl_xor(x, 32, 64));
  return x;
}

// ---- prep_te: te table over the whole vocab + WHT/WREL frag packing -------
// te[v] = tanh(emb[v]@W_trans + b_trans)  (bf16).  417 blocks x 512 threads
// (8 waves), 96 consecutive vocab rows each — >1.6 blocks/CU for latency
// overlap.  W_trans frags built per-wave from global f32 (f2bf — bit-identical
// to a packed path).  Blocks 0..11 additionally pack the WHT/WREL fragments
// for fused (verbatim slot math, 512 slots each).
__launch_bounds__(512, 8)
__global__ void prep_te(const float* __restrict__ emb_f32,
                        const float* __restrict__ Wt,
                        const float* __restrict__ Wht,
                        const float* __restrict__ Wrel,
                        const float* __restrict__ b_trans,
                        unsigned char* __restrict__ ws,
                        unsigned short* __restrict__ te_g) {
  __shared__ unsigned short TEB[96 * 128];   // 24KB
  const int tid  = threadIdx.x;
  const int base = blockIdx.x * 96;
  const int w    = tid >> 6;      // wave 0..7
  const int lane = tid & 63;
  const int li   = lane & 15;
  const int lg   = lane >> 4;
  const int nt   = w;             // wave owns n-tile w, all 6 row-tiles

  // stage 96 consecutive emb rows (f32 -> bf16, swizzled source chunk)
  float4 xv[3], yv[3];
  #pragma unroll
  for (int j = 0; j < 3; ++j) {
    int o = tid + j * 512, row = o >> 4, pc = o & 15;
    int grow = base + row; if (grow > NV - 1) grow = NV - 1;
    int clog = pc ^ (row & 15);
    const float* fb = emb_f32 + (size_t)grow * UU + clog * 8;
    xv[j] = *reinterpret_cast<const float4*>(fb);
    yv[j] = *reinterpret_cast<const float4*>(fb + 4);
  }
  // W_trans frags direct from global: B1h[kt][j] = bf16(Wt[(kt*32+lg*8+j)*128
  // + nt*16+li]) — identical values to the packed path.
  short8 B1h[4];
  #pragma unroll
  for (int kt = 0; kt < 4; ++kt) {
    #pragma unroll
    for (int j = 0; j < 8; ++j)
      B1h[kt][j] = (short)f2bf(Wt[(size_t)(kt * 32 + lg * 8 + j) * UU + nt * 16 + li]);
  }
  #pragma unroll
  for (int j = 0; j < 3; ++j) {
    int o = tid + j * 512;
    uint4 pk = { cvtpk(xv[j].x, xv[j].y), cvtpk(xv[j].z, xv[j].w),
                 cvtpk(yv[j].x, yv[j].y), cvtpk(yv[j].z, yv[j].w) };
    *reinterpret_cast<uint4*>(&TEB[o * 8]) = pk;
  }
  const float4 btr4 = *reinterpret_cast<const float4*>(b_trans + nt * 16 + lg * 4);
  __syncthreads();

  // GEMM1: 6 row-tiles x 4 kt per wave (verified swizzle: row&15 == li)
  f32x4 acc[6];
  #pragma unroll
  for (int q = 0; q < 6; ++q) acc[q] = f32x4{0.f, 0.f, 0.f, 0.f};
  #pragma unroll
  for (int kt = 0; kt < 4; ++kt) {
    #pragma unroll
    for (int q = 0; q < 6; ++q) {
      const short8 b = *reinterpret_cast<const short8*>(
          &TEB[(q * 16 + li) * 128 + (((kt * 4 + lg) ^ li) << 3)]);
      acc[q] = __builtin_amdgcn_mfma_f32_16x16x32_bf16(B1h[kt], b, acc[q], 0, 0, 0);
    }
  }

  // epilogue: tanh + bias -> global te table (bf16 pairs)
  #pragma unroll
  for (int q = 0; q < 6; ++q) {
    int row  = q * 16 + li;
    int grow = base + row; if (grow > NV - 1) grow = NV - 1;  // dup write, same value
    float v0 = ftanh(acc[q][0] + btr4.x);
    float v1 = ftanh(acc[q][1] + btr4.y);
    float v2 = ftanh(acc[q][2] + btr4.z);
    float v3 = ftanh(acc[q][3] + btr4.w);
    uint2 pk = { cvtpk(v0, v1), cvtpk(v2, v3) };
    *reinterpret_cast<uint2*>(te_g + (size_t)grow * UU + nt * 16 + lg * 4) = pk;
  }

  // blocks 0..11: pack WHT (4096 slots) + WREL (2048 slots) for fused
  if (blockIdx.x < 12) {
    int slot = blockIdx.x * 512 + tid;          // 0..6143
    const float* W;
    unsigned char* fb;
    if (slot < 4096) { W = Wht;  fb = ws + WHT_OFF; }
    else             { W = Wrel; fb = ws + WREL_OFF; slot -= 4096; }
    int ln = slot & 63, pair = slot >> 6;
    int n  = (pair & 7) * 16 + (ln & 15);
    int k0 = (pair >> 3) * 32 + (ln >> 4) * 8;
    short8 hv;
    #pragma unroll
    for (int j = 0; j < 8; ++j)
      hv[j] = (short)f2bf(W[(size_t)(k0 + j) * UU + n]);
    *reinterpret_cast<short8*>(fb + (size_t)pair * 1024 + ln * 16) = hv;
  }
}

// ---- fused per-(b,t) kernel: 1024 blocks x 1024 threads (16 waves) ---------
// Gathers pre-transformed te rows (bf16) into TEB, GEMM2, softmax, wsum,
// scatter.  Barriers: 3.  TEB swizzle: logical 16B-chunk c16 of row r at
// physical chunk c16^(r&15).
__launch_bounds__(1024, 8)
__global__ void fused_bt(const int* __restrict__ triples,
                         const unsigned short* __restrict__ te_g,
                         const float* __restrict__ b_ht,
                         const float* __restrict__ b_rel,
                         const int* __restrict__ sent_triples,
                         const unsigned char* __restrict__ wsr,
                         float* __restrict__ out) {
  __shared__ unsigned short TEB[192 * 128];    // 48KB: te rows (bf16)
  __shared__ float EWt[8][64];                 // e_weight partials
  __shared__ float PART[8][256];               // wsum partials (8 l-groups)
  __shared__ int MATCH[512];
  __shared__ int NM;

  const int tid  = threadIdx.x;
  const int bt   = blockIdx.x;
  const int w    = tid >> 6;
  const int lane = tid & 63;
  const int li   = lane & 15;
  const int lg   = lane >> 4;
  const int nt   = w & 7;
  const int rh   = w >> 3;

  // tokens per-thread direct (R6-verified broadcast-coalesced pattern)
  int tok[3];
  #pragma unroll
  for (int j = 0; j < 3; ++j) {
    int row = (tid + j * 1024) >> 4;
    tok[j] = triples[(size_t)bt * 192 + row];
  }
  int sidx = -1;
  if (tid < SS) sidx = sent_triples[(size_t)(bt >> 6) * SS + tid];
  if (tid == 0) NM = 0;

  // ---- stage 192 te rows (bf16, 16B/slot) --------------------------------
  short8 sv[3];
  #pragma unroll
  for (int j = 0; j < 3; ++j) {
    int o = tid + j * 1024, row = o >> 4, pc = o & 15;
    int clog = pc ^ (row & 15);
    sv[j] = *reinterpret_cast<const short8*>(
        te_g + (size_t)tok[j] * UU + clog * 8);
  }
  #pragma unroll
  for (int j = 0; j < 3; ++j)
    *reinterpret_cast<short8*>(&TEB[(tid + j * 1024) * 8]) = sv[j];

  const unsigned char* whtb = wsr + WHT_OFF;
  const unsigned char* wrlb = wsr + WREL_OFF;
  const float bhv  = b_ht[nt * 16 + li];
  const float brlv = b_rel[nt * 16 + li];
  // prefetch GEMM2 first W-frag before the barrier
  short8 Wc = *reinterpret_cast<const short8*>(
      whtb + (size_t)nt * 1024 + lane * 16);
  __syncthreads();  // (b1) staging complete; NM=0 visible

  // ---- match-find: overlaps GEMM2 (MATCH/NM not read until scatter) ------
  if (sidx == (bt & 63))
    MATCH[atomicAdd(&NM, 1)] = tid;

  // ============ GEMM2: ht_t / rel_t / e_weight (2 m-tiles per wave) =======
  // head = te row 3l+0, rel = 3l+1, tail = 3l+2  (l = m*16 + li)
  const int mh = rh * 2;
  f32x4 accH[2] = {{0.f,0.f,0.f,0.f},{0.f,0.f,0.f,0.f}};
  f32x4 accR[2] = {{0.f,0.f,0.f,0.f},{0.f,0.f,0.f,0.f}};

  #pragma unroll
  for (int kt = 0; kt < 8; ++kt) {   // head_tail: K=256
    short8 Wn;
    if (kt < 7)
      Wn = *reinterpret_cast<const short8*>(
          whtb + (size_t)((kt + 1) * 8 + nt) * 1024 + lane * 16);
    else
      Wn = *reinterpret_cast<const short8*>(
          wrlb + (size_t)nt * 1024 + lane * 16);
    const int koff = (kt < 4) ? 0 : 2;
    const int c16  = (kt & 3) * 4 + lg;
    #pragma unroll
    for (int mi = 0; mi < 2; ++mi) {
      const int row = 48 * (mh + mi) + 3 * li + koff;
      const short8 a = *reinterpret_cast<const short8*>(
          &TEB[row * 128 + ((c16 ^ (row & 15)) << 3)]);
      accH[mi] = __builtin_amdgcn_mfma_f32_16x16x32_bf16(a, Wc, accH[mi], 0, 0, 0);
    }
    Wc = Wn;
  }
  #pragma unroll
  for (int kt = 0; kt < 4; ++kt) {   // relation: K=128, rows 3l+1
    short8 Wn;
    if (kt < 3)
      Wn = *reinterpret_cast<const short8*>(
          wrlb + (size_t)((kt + 1) * 8 + nt) * 1024 + lane * 16);
    const int c16 = kt * 4 + lg;
    #pragma unroll
    for (int mi = 0; mi < 2; ++mi) {
      const int row = 48 * (mh + mi) + 3 * li + 1;
      const short8 a = *reinterpret_cast<const short8*>(
          &TEB[row * 128 + ((c16 ^ (row & 15)) << 3)]);
      accR[mi] = __builtin_amdgcn_mfma_f32_16x16x32_bf16(a, Wc, accR[mi], 0, 0, 0);
    }
    Wc = Wn;
  }

  // e_weight partials: l = (mh+mi)*16 + lg*4 + r; DPP-reduce over 16 u lanes
  #pragma unroll
  for (int mi = 0; mi < 2; ++mi) {
    #pragma unroll
    for (int r = 0; r < 4; ++r) {
      float p = ftanh(accH[mi][r] + bhv) * (accR[mi][r] + brlv);
      p = row16_sum(p);
      if (li == 0) EWt[nt][(mh + mi) * 16 + lg * 4 + r] = p;
    }
  }
  __syncthreads();  // (b2) EWt ready

  // ============ redundant softmax (every wave; no barrier after) ==========
  float alpha;
  {
    float e = 0.f;
    #pragma unroll
    for (int n = 0; n < 8; ++n) e += EWt[n][lane];
    float mx = full64_max(e);
    float ex = __expf(e - mx);
    float sm = full64_sum(ex);
    alpha = ex / sm;
  }

  // ============ weighted sum: paired-bf16 b32 reads, 8 l's per thread ======
  {
    int cp  = tid & 127, lgp = w >> 1;
    int c0  = cp << 1;
    int k   = (c0 >> 7) << 1;              // head rows 3l, tail rows 3l+2
    int cc  = c0 & 127;
    int w8  = cc >> 3, bofs = (cc & 7) << 1;
    float o0 = 0.f, o1 = 0.f;
    #pragma unroll
    for (int j = 0; j < 8; ++j) {
      int l = lgp * 8 + j;
      float al = __int_as_float(
          __builtin_amdgcn_readlane(__float_as_int(alpha), l));
      int row = 3 * l + k;
      unsigned u = *reinterpret_cast<const unsigned*>(
          reinterpret_cast<const char*>(TEB) + row * 256 +
          (((w8 ^ (row & 15)) << 4) | bofs));
      o0 = fmaf(al, __uint_as_float(u << 16), o0);
      o1 = fmaf(al, __uint_as_float(u & 0xFFFF0000u), o1);
    }
    *reinterpret_cast<float2*>(&PART[lgp][c0]) = make_float2(o0, o1);
  }
  __syncthreads();  // (b3) PART ready; MATCH/NM final

  // ============ scatter: participating waves fold the 8-way reduce ========
  {
    const int b  = bt >> 6;
    const int nm = NM;
    if (w < nm) {
      float4 v = {0.f, 0.f, 0.f, 0.f};
      #pragma unroll
      for (int g = 0; g < 8; ++g) {
        float4 p = reinterpret_cast<const float4*>(&PART[g][0])[lane];
        v.x += p.x; v.y += p.y; v.z += p.z; v.w += p.w;
      }
      for (int q = w; q < nm; q += 16) {
        int s = MATCH[q];
        reinterpret_cast<float4*>(out + ((size_t)(b * SS + s)) * 256)[lane] = v;
      }
    }
  }
}

extern "C" void kernel_launch(void* const* d_in, const int* in_sizes, int n_in,
                              void* d_out, int out_size, void* d_ws, size_t ws_size,
                              hipStream_t stream) {
  const int*   triples      = (const int*)d_in[1];
  const int*   sent_triples = (const int*)d_in[2];
  const float* emb_table    = (const float*)d_in[3];
  const float* W_trans      = (const float*)d_in[4];
  const float* b_trans      = (const float*)d_in[5];
  const float* W_ht         = (const float*)d_in[6];
  const float* b_ht         = (const float*)d_in[7];
  const float* W_rel        = (const float*)d_in[8];
  const float* b_rel        = (const float*)d_in[9];
  float* out = (float*)d_out;
  unsigned char* ws = (unsigned char*)d_ws;
  unsigned short* te_g = (unsigned short*)(ws + TE_OFF);

  prep_te<<<(NV + 95) / 96, 512, 0, stream>>>(
      emb_table, W_trans, W_ht, W_rel, b_trans, ws, te_g);
  fused_bt<<<BB * TT, 1024, 0, stream>>>(
      triples, te_g, b_ht, b_rel, sent_triples, ws, out);
}